// Round 5
// baseline (428.050 us; speedup 1.0000x reference)
//
#include <hip/hip_runtime.h>

// Problem constants (from reference)
#define B_  16
#define T_  2048
#define IN_ 512
#define H_  512
#define M_  (B_ * T_)

// GEMM tiling — R5 structure, the measured local optimum (~208us, VGPR 116).
// History: R6 (256,4) bound -> acc spill -> 3048us. R7 2-reg-set ping-pong
// -> VGPR 192 -> 298us. R8 persistent fusion -> occupancy coupling -> 529us.
// R9 1-barrier ping-pong -> mid-compute vmcnt drain -> 230us.
// R13 split into half-grids (instrumentation): cost +14us -> REVERTED.
// R13's finding: gif_scan dispatch is < 112us (absent from duration-sorted
// top-5 vs 112us half-GEMMs) -> the ~158us "scan" inferred from wall-time
// subtraction included ~40-55us of launch/memset overhead. KEEP SINGLE LAUNCH.
#define BM 128
#define BN 128
#define BK 16
#define LDT (BM + 4)

static __device__ __forceinline__ float4 ld4(const float* p) {
    return *reinterpret_cast<const float4*>(p);
}

// ---------------------------------------------------------------------------
// Kernel 1: h[m][n] = sum_k x[m][k]*W[n][k] + b[n], fp32 VALU.
// k accumulated strictly in order 0..511 with fmaf -> bit-matches np ref
// (absmax 0.0 across R2-R13). DO NOT reorder the k loop.
// BYTE-IDENTICAL to the validated single-launch kernel.
// ---------------------------------------------------------------------------
__global__ __launch_bounds__(256)
void gemm_xwT(const float* __restrict__ X, const float* __restrict__ W,
              const float* __restrict__ bias, float* __restrict__ Hout) {
    __shared__ float As[BK][LDT];
    __shared__ float Bs[BK][LDT];

    const int tid = threadIdx.x;
    const int m0  = blockIdx.x * BM;   // 256 m-tiles
    const int n0  = blockIdx.y * BN;   // 4 n-tiles

    const int tx = tid & 15;           // col group
    const int ty = tid >> 4;           // row group

    const int row = tid >> 2;          // 0..63
    const int kph = (tid & 3) * 4;     // 0,4,8,12

    const float* pa0 = X + (size_t)(m0 + row) * IN_ + kph;
    const float* pa1 = pa0 + (size_t)64 * IN_;
    const float* pb0 = W + (size_t)(n0 + row) * IN_ + kph;
    const float* pb1 = pb0 + (size_t)64 * IN_;

    float4 ra0 = ld4(pa0), ra1 = ld4(pa1), rb0 = ld4(pb0), rb1 = ld4(pb1);

    float acc[8][8];
#pragma unroll
    for (int i = 0; i < 8; ++i)
#pragma unroll
        for (int j = 0; j < 8; ++j) acc[i][j] = 0.0f;

    for (int k0 = 0; k0 < IN_; k0 += BK) {
        As[kph + 0][row]      = ra0.x;  As[kph + 1][row]      = ra0.y;
        As[kph + 2][row]      = ra0.z;  As[kph + 3][row]      = ra0.w;
        As[kph + 0][row + 64] = ra1.x;  As[kph + 1][row + 64] = ra1.y;
        As[kph + 2][row + 64] = ra1.z;  As[kph + 3][row + 64] = ra1.w;
        Bs[kph + 0][row]      = rb0.x;  Bs[kph + 1][row]      = rb0.y;
        Bs[kph + 2][row]      = rb0.z;  Bs[kph + 3][row]      = rb0.w;
        Bs[kph + 0][row + 64] = rb1.x;  Bs[kph + 1][row + 64] = rb1.y;
        Bs[kph + 2][row + 64] = rb1.z;  Bs[kph + 3][row + 64] = rb1.w;
        __syncthreads();

        // prefetch next k-tile into registers; drains during the 16-k compute
        if (k0 + BK < IN_) {
            ra0 = ld4(pa0 + k0 + BK);  ra1 = ld4(pa1 + k0 + BK);
            rb0 = ld4(pb0 + k0 + BK);  rb1 = ld4(pb1 + k0 + BK);
        }

#pragma unroll
        for (int k = 0; k < BK; ++k) {
            float4 av0 = ld4(&As[k][ty * 4]);
            float4 av1 = ld4(&As[k][ty * 4 + 64]);
            float4 bv0 = ld4(&Bs[k][tx * 4]);
            float4 bv1 = ld4(&Bs[k][tx * 4 + 64]);
            const float am[8] = {av0.x, av0.y, av0.z, av0.w,
                                 av1.x, av1.y, av1.z, av1.w};
            const float bn8[8] = {bv0.x, bv0.y, bv0.z, bv0.w,
                                  bv1.x, bv1.y, bv1.z, bv1.w};
#pragma unroll
            for (int i = 0; i < 8; ++i)
#pragma unroll
                for (int j = 0; j < 8; ++j)
                    acc[i][j] = fmaf(am[i], bn8[j], acc[i][j]);
        }
        __syncthreads();
    }

    // epilogue: + bias (bias is zeros -> exact), coalesced float4 stores
    float4 bb0 = ld4(&bias[n0 + tx * 4]);
    float4 bb1 = ld4(&bias[n0 + tx * 4 + 64]);
#pragma unroll
    for (int i = 0; i < 8; ++i) {
        const int r = m0 + ((i < 4) ? (ty * 4 + i) : (64 + ty * 4 + (i - 4)));
        float4 o0, o1;
        o0.x = acc[i][0] + bb0.x;  o0.y = acc[i][1] + bb0.y;
        o0.z = acc[i][2] + bb0.z;  o0.w = acc[i][3] + bb0.w;
        o1.x = acc[i][4] + bb1.x;  o1.y = acc[i][5] + bb1.y;
        o1.z = acc[i][6] + bb1.z;  o1.w = acc[i][7] + bb1.w;
        *reinterpret_cast<float4*>(&Hout[(size_t)r * H_ + n0 + tx * 4])      = o0;
        *reinterpret_cast<float4*>(&Hout[(size_t)r * H_ + n0 + tx * 4 + 64]) = o1;
    }
}

// ---------------------------------------------------------------------------
// Kernel 2: GIF neuron scan. R14: TWO chains per thread, interleaved in the
// same inner-loop body. 4096 threads x 2 (b,h) chains (h and h+256, same b).
// Rationale (R13 finding): scan dispatch < 112us, i.e. <= ~130 cy/step, while
// the dep-chain floor is ~50 cy/step and issue is ~28 cy/step -> if the gap
// is ILP-absorbable lone-wave stall, interleaving a second independent chain
// fills it (2-chain issue ~56 cy/step-slot, chain latency unchanged).
// If null -> scan is provably at its dependence/issue wall.
// Per-chain statement order BYTE-IDENTICAL to the validated R10-R13 step ->
// bit-exact by construction. DO NOT touch the arithmetic statements.
// SPF=16 keeps the 4 double-buffers at ~128 VGPR (no spill at 1 wave/SIMD).
// ---------------------------------------------------------------------------
#define SPF 16

__device__ __forceinline__
void scan_step(float cur, float& v, float& theta, float& s_out) {
    const float DECAY_F = 0.9048374180359595f;  // exp(-1/10)
    const float ALPHA_F = 0.01f;
    v = v * DECAY_F + cur;
    float cl = 32.0f * theta;                  // L * theta * 2
    v = __builtin_amdgcn_fmed3f(v, -cl, cl);   // == fminf(fmaxf(v,-cl),cl)

    // ---- v/theta: raw rcp seed + Markstein correction (validated) ----
    float r0 = __builtin_amdgcn_rcpf(theta);   // ~1 ulp seed
    float q0 = v * r0;
    float er = fmaf(-theta, q0, v);            // exact residual
    float q  = fmaf(er, r0, q0);               // RN quotient to O(ulp^2)
    // ------------------------------------------------------------------

    float s = floorf(q);
    s = __builtin_amdgcn_fmed3f(s, 0.0f, 16.0f); // == fminf(fmaxf(s,0),16)
    v = v - s * theta;
    theta = theta + ALPHA_F * s - ALPHA_F * (theta - 1.0f);
    s_out = s;
}

__device__ __forceinline__
void scan2(const float* __restrict__ b0, const float* __restrict__ b1,
           float* __restrict__ s0, float* __restrict__ s1,
           float& v0, float& th0, float& v1, float& th1) {
#pragma unroll
    for (int j = 0; j < SPF; ++j) {
        // two independent chains in one body -> scheduler interleaves,
        // each chain's dependent stalls filled by the other's ops
        scan_step(b0[j], v0, th0, s0[j]);
        scan_step(b1[j], v1, th1, s1[j]);
    }
}

__global__ __launch_bounds__(64, 1)
void gif_scan(const float* __restrict__ Hbuf, float* __restrict__ spikes,
              float* __restrict__ vout, float* __restrict__ thout) {
    const int gid = blockIdx.x * 64 + threadIdx.x;    // 0..4095
    const int b  = gid >> 8;                          // 16 b's x 256 threads
    const int h0 = gid & 255;                         // chain0: h0, chain1: h0+256

    const float* ip0 = Hbuf   + (size_t)b * T_ * H_ + h0;
    const float* ip1 = ip0 + 256;
    float*       sp0 = spikes + (size_t)b * T_ * H_ + h0;
    float*       sp1 = sp0 + 256;

    float bufA0[SPF], bufA1[SPF], bufB0[SPF], bufB1[SPF];
    float sA0[SPF], sA1[SPF], sB0[SPF], sB1[SPF];

#pragma unroll
    for (int j = 0; j < SPF; ++j) {
        bufA0[j] = ip0[(size_t)j * H_];
        bufA1[j] = ip1[(size_t)j * H_];
    }

    float v0 = 0.0f, th0 = 1.0f, v1 = 0.0f, th1 = 1.0f;
    for (int t0 = 0; t0 < T_; t0 += 2 * SPF) {        // 64 iters, no tail
        // prefetch next half-batch for both chains
#pragma unroll
        for (int j = 0; j < SPF; ++j) {
            bufB0[j] = ip0[(size_t)(t0 + SPF + j) * H_];
            bufB1[j] = ip1[(size_t)(t0 + SPF + j) * H_];
        }
        asm volatile("" ::: "memory");

        scan2(bufA0, bufA1, sA0, sA1, v0, th0, v1, th1);
#pragma unroll
        for (int j = 0; j < SPF; ++j) {
            sp0[(size_t)(t0 + j) * H_] = sA0[j];
            sp1[(size_t)(t0 + j) * H_] = sA1[j];
        }

        if (t0 + 2 * SPF < T_) {
#pragma unroll
            for (int j = 0; j < SPF; ++j) {
                bufA0[j] = ip0[(size_t)(t0 + 2 * SPF + j) * H_];
                bufA1[j] = ip1[(size_t)(t0 + 2 * SPF + j) * H_];
            }
        }
        asm volatile("" ::: "memory");

        scan2(bufB0, bufB1, sB0, sB1, v0, th0, v1, th1);
#pragma unroll
        for (int j = 0; j < SPF; ++j) {
            sp0[(size_t)(t0 + SPF + j) * H_] = sB0[j];
            sp1[(size_t)(t0 + SPF + j) * H_] = sB1[j];
        }
    }
    vout[(size_t)b * H_ + h0]       = v0;
    thout[(size_t)b * H_ + h0]      = th0;
    vout[(size_t)b * H_ + h0 + 256] = v1;
    thout[(size_t)b * H_ + h0 + 256]= th1;
}

// ---------------------------------------------------------------------------
extern "C" void kernel_launch(void* const* d_in, const int* in_sizes, int n_in,
                              void* d_out, int out_size, void* d_ws, size_t ws_size,
                              hipStream_t stream) {
    const float* x    = (const float*)d_in[0];   // [16, 2048, 512]
    const float* W    = (const float*)d_in[1];   // [512, 512]
    const float* bias = (const float*)d_in[2];   // [512]

    float* out    = (float*)d_out;
    float* spikes = out;
    float* v_f    = out + (size_t)M_ * H_;
    float* th_f   = v_f + (size_t)B_ * H_;

    float* hbuf   = (float*)d_ws;                // 64 MiB scratch for h

    dim3 grid(M_ / BM, H_ / BN);                 // 256 x 4, single launch
    gemm_xwT<<<grid, 256, 0, stream>>>(x, W, bias, hbuf);
    gif_scan<<<(B_ * H_) / 2 / 64, 64, 0, stream>>>(hbuf, spikes, v_f, th_f);
}

// Round 6
// 368.585 us; speedup vs baseline: 1.1613x; 1.1613x over previous
//
#include <hip/hip_runtime.h>

// Problem constants (from reference)
#define B_  16
#define T_  2048
#define IN_ 512
#define H_  512
#define M_  (B_ * T_)

// GEMM tiling — R5 structure, the measured local optimum (~207us, VGPR 116).
// History: R6 (256,4) bound -> acc spill -> 3048us. R7 2-reg-set ping-pong
// -> VGPR 192 -> 298us. R8 persistent fusion -> occupancy coupling -> 529us.
// R9 1-barrier ping-pong -> mid-compute vmcnt drain -> 230us.
// R13 half-grid split (instrumentation): +14us -> reverted. Finding: scan
// dispatch < 112us; ~50us of wall is launch/memset overhead.
// R14 2-chain-per-thread scan: compiler serialized the chains -> 428us ->
// REVERTED. Scan stays in R11 form (session best: 368.7us).
// R15: XCD-aware block swizzle in GEMM. FETCH=122.5MB vs 65MB ideal = the 4
// same-m0 blocks (sharing 256KB of X rows) scattered across per-XCD L2s.
// Remap linear id L = m%8 + 8*(4*(m/8)+n) (bijective, 128 blocks/XCD) so all
// 4 n-tiles of an m-tile land on ONE XCD -> X fetched once per XCD.
// Per-tile arithmetic and k-order untouched -> bit-exact by construction.
#define BM 128
#define BN 128
#define BK 16
#define LDT (BM + 4)

static __device__ __forceinline__ float4 ld4(const float* p) {
    return *reinterpret_cast<const float4*>(p);
}

// ---------------------------------------------------------------------------
// Kernel 1: h[m][n] = sum_k x[m][k]*W[n][k] + b[n], fp32 VALU.
// k accumulated strictly in order 0..511 with fmaf -> bit-matches np ref
// (absmax 0.0 across R2-R14). DO NOT reorder the k loop.
// Body verbatim from the validated kernel; ONLY the m0/n0 derivation changed
// (XCD swizzle of blockIdx -> tile assignment).
// ---------------------------------------------------------------------------
__global__ __launch_bounds__(256)
void gemm_xwT(const float* __restrict__ X, const float* __restrict__ W,
              const float* __restrict__ bias, float* __restrict__ Hout) {
    __shared__ float As[BK][LDT];
    __shared__ float Bs[BK][LDT];

    const int tid = threadIdx.x;

    // XCD-aware swizzle: dispatch round-robins linear id across 8 XCDs.
    // L = (m%8) + 8*(4*(m/8) + n)  =>  inverse below. Same m-tile => same
    // L%8 => same XCD => its 4 n-tile blocks share X rows in one L2.
    const int L  = blockIdx.y * gridDim.x + blockIdx.x;   // 0..1023
    const int r  = L & 7;
    const int q  = L >> 3;
    const int mt = r + 8 * (q >> 2);   // 0..255
    const int nt = q & 3;              // 0..3
    const int m0 = mt * BM;
    const int n0 = nt * BN;

    const int tx = tid & 15;           // col group
    const int ty = tid >> 4;           // row group

    const int row = tid >> 2;          // 0..63
    const int kph = (tid & 3) * 4;     // 0,4,8,12

    const float* pa0 = X + (size_t)(m0 + row) * IN_ + kph;
    const float* pa1 = pa0 + (size_t)64 * IN_;
    const float* pb0 = W + (size_t)(n0 + row) * IN_ + kph;
    const float* pb1 = pb0 + (size_t)64 * IN_;

    float4 ra0 = ld4(pa0), ra1 = ld4(pa1), rb0 = ld4(pb0), rb1 = ld4(pb1);

    float acc[8][8];
#pragma unroll
    for (int i = 0; i < 8; ++i)
#pragma unroll
        for (int j = 0; j < 8; ++j) acc[i][j] = 0.0f;

    for (int k0 = 0; k0 < IN_; k0 += BK) {
        As[kph + 0][row]      = ra0.x;  As[kph + 1][row]      = ra0.y;
        As[kph + 2][row]      = ra0.z;  As[kph + 3][row]      = ra0.w;
        As[kph + 0][row + 64] = ra1.x;  As[kph + 1][row + 64] = ra1.y;
        As[kph + 2][row + 64] = ra1.z;  As[kph + 3][row + 64] = ra1.w;
        Bs[kph + 0][row]      = rb0.x;  Bs[kph + 1][row]      = rb0.y;
        Bs[kph + 2][row]      = rb0.z;  Bs[kph + 3][row]      = rb0.w;
        Bs[kph + 0][row + 64] = rb1.x;  Bs[kph + 1][row + 64] = rb1.y;
        Bs[kph + 2][row + 64] = rb1.z;  Bs[kph + 3][row + 64] = rb1.w;
        __syncthreads();

        // prefetch next k-tile into registers; drains during the 16-k compute
        if (k0 + BK < IN_) {
            ra0 = ld4(pa0 + k0 + BK);  ra1 = ld4(pa1 + k0 + BK);
            rb0 = ld4(pb0 + k0 + BK);  rb1 = ld4(pb1 + k0 + BK);
        }

#pragma unroll
        for (int k = 0; k < BK; ++k) {
            float4 av0 = ld4(&As[k][ty * 4]);
            float4 av1 = ld4(&As[k][ty * 4 + 64]);
            float4 bv0 = ld4(&Bs[k][tx * 4]);
            float4 bv1 = ld4(&Bs[k][tx * 4 + 64]);
            const float am[8] = {av0.x, av0.y, av0.z, av0.w,
                                 av1.x, av1.y, av1.z, av1.w};
            const float bn8[8] = {bv0.x, bv0.y, bv0.z, bv0.w,
                                  bv1.x, bv1.y, bv1.z, bv1.w};
#pragma unroll
            for (int i = 0; i < 8; ++i)
#pragma unroll
                for (int j = 0; j < 8; ++j)
                    acc[i][j] = fmaf(am[i], bn8[j], acc[i][j]);
        }
        __syncthreads();
    }

    // epilogue: + bias (bias is zeros -> exact), coalesced float4 stores
    float4 bb0 = ld4(&bias[n0 + tx * 4]);
    float4 bb1 = ld4(&bias[n0 + tx * 4 + 64]);
#pragma unroll
    for (int i = 0; i < 8; ++i) {
        const int r2 = m0 + ((i < 4) ? (ty * 4 + i) : (64 + ty * 4 + (i - 4)));
        float4 o0, o1;
        o0.x = acc[i][0] + bb0.x;  o0.y = acc[i][1] + bb0.y;
        o0.z = acc[i][2] + bb0.z;  o0.w = acc[i][3] + bb0.w;
        o1.x = acc[i][4] + bb1.x;  o1.y = acc[i][5] + bb1.y;
        o1.z = acc[i][6] + bb1.z;  o1.w = acc[i][7] + bb1.w;
        *reinterpret_cast<float4*>(&Hout[(size_t)r2 * H_ + n0 + tx * 4])      = o0;
        *reinterpret_cast<float4*>(&Hout[(size_t)r2 * H_ + n0 + tx * 4 + 64]) = o1;
    }
}

// ---------------------------------------------------------------------------
// Kernel 2: GIF neuron scan. One thread per (b,h) chain; T=2048 steps.
// R11 form — the session-best validated version (368.7us total). 128 waves,
// register double-buffers, pure-ALU compute phase, bulk batch stores.
// R10-R14 established: not ALU-chain-bound, not store-hazard-bound, not
// vmem-count-bound, not per-thread-ILP-improvable. LEAVE AS IS.
// Arithmetic statements byte-identical to R10-R14 (absmax 0.0). DO NOT touch.
// ---------------------------------------------------------------------------
#define SPF 32

__device__ __forceinline__
void scan_compute(const float* __restrict__ buf, float* __restrict__ sarr,
                  float& v, float& theta) {
    const float DECAY_F = 0.9048374180359595f;  // exp(-1/10)
    const float ALPHA_F = 0.01f;
#pragma unroll
    for (int j = 0; j < SPF; ++j) {
        float cur = buf[j];
        v = v * DECAY_F + cur;
        float cl = 32.0f * theta;                  // L * theta * 2
        v = __builtin_amdgcn_fmed3f(v, -cl, cl);   // == fminf(fmaxf(v,-cl),cl)

        // ---- v/theta: raw rcp seed + Markstein correction (validated) ----
        float r0 = __builtin_amdgcn_rcpf(theta);   // ~1 ulp seed
        float q0 = v * r0;
        float er = fmaf(-theta, q0, v);            // exact residual
        float q  = fmaf(er, r0, q0);               // RN quotient to O(ulp^2)
        // ------------------------------------------------------------------

        float s = floorf(q);
        s = __builtin_amdgcn_fmed3f(s, 0.0f, 16.0f); // == fminf(fmaxf(s,0),16)
        v = v - s * theta;
        theta = theta + ALPHA_F * s - ALPHA_F * (theta - 1.0f);
        sarr[j] = s;                               // register array, no store
    }
}

__device__ __forceinline__
void store_batch(float* __restrict__ sp, int tb, const float* __restrict__ sarr) {
#pragma unroll
    for (int j = 0; j < SPF; ++j)
        sp[(size_t)(tb + j) * H_] = sarr[j];
}

__global__ __launch_bounds__(64, 1)
void gif_scan(const float* __restrict__ Hbuf, float* __restrict__ spikes,
              float* __restrict__ vout, float* __restrict__ thout) {
    const int gid = blockIdx.x * 64 + threadIdx.x;    // 0..8191
    const int b = gid >> 9;
    const int h = gid & 511;

    const float* ip = Hbuf   + (size_t)b * T_ * H_ + h;
    float*       sp = spikes + (size_t)b * T_ * H_ + h;

    float bufA[SPF], bufB[SPF], sA[SPF], sB[SPF];
#pragma unroll
    for (int j = 0; j < SPF; ++j) bufA[j] = ip[(size_t)j * H_];

    float v = 0.0f, theta = 1.0f;
    for (int t0 = 0; t0 < T_; t0 += 2 * SPF) {        // 32 iters, no tail
        // prefetch next half-batch
#pragma unroll
        for (int j = 0; j < SPF; ++j) bufB[j] = ip[(size_t)(t0 + SPF + j) * H_];
        asm volatile("" ::: "memory");

        scan_compute(bufA, sA, v, theta);             // pure ALU
        store_batch(sp, t0, sA);                      // 32 bulk stores

        if (t0 + 2 * SPF < T_) {
#pragma unroll
            for (int j = 0; j < SPF; ++j)
                bufA[j] = ip[(size_t)(t0 + 2 * SPF + j) * H_];
        }
        asm volatile("" ::: "memory");

        scan_compute(bufB, sB, v, theta);             // pure ALU
        store_batch(sp, t0 + SPF, sB);                // 32 bulk stores
    }
    vout[gid]  = v;
    thout[gid] = theta;
}

// ---------------------------------------------------------------------------
extern "C" void kernel_launch(void* const* d_in, const int* in_sizes, int n_in,
                              void* d_out, int out_size, void* d_ws, size_t ws_size,
                              hipStream_t stream) {
    const float* x    = (const float*)d_in[0];   // [16, 2048, 512]
    const float* W    = (const float*)d_in[1];   // [512, 512]
    const float* bias = (const float*)d_in[2];   // [512]

    float* out    = (float*)d_out;
    float* spikes = out;
    float* v_f    = out + (size_t)M_ * H_;
    float* th_f   = v_f + (size_t)B_ * H_;

    float* hbuf   = (float*)d_ws;                // 64 MiB scratch for h

    dim3 grid(M_ / BM, H_ / BN);                 // 256 x 4, single launch
    gemm_xwT<<<grid, 256, 0, stream>>>(x, W, bias, hbuf);
    gif_scan<<<(B_ * H_) / 64, 64, 0, stream>>>(hbuf, spikes, v_f, th_f);
}